// Round 10
// baseline (169.182 us; speedup 1.0000x reference)
//
#include <hip/hip_runtime.h>

// SatelliteCBF V_with_jacobian, MI355X — round 6 kernel, fourth resubmit
// (R6/R7/R8/R9 benches all died on GPUAcquisitionTimeout — infra, not
// kernel. Resubmitting byte-identical for clean attribution of the spill
// fix.)
//
// R5 post-mortem: __launch_bounds__(512,2) empirically capped VGPR at 128;
// live state needs ~230 -> ~100 MB/dispatch scratch traffic (WRITE_SIZE
// evidence). R6: (512,1) -> no cap, no spill, 2 waves/SIMD. Main kernel
// otherwise IDENTICAL to R5 (passed, absmax 0.0078). Setup kernel rewritten:
// one thread = one 8-element fragment, coalesced 16B stores (was ~25us of
// scattered 2B stores; target <8us).
//
// Structure recap: per-wave-full-layer, register-resident activations.
// 8 waves x 16 samples; wave computes all 128 h of a layer via 16x16x32
// bf16 MFMA, two-term split (wa*xa + wa*xb + wb*xa), D-factors exact in
// f32 regs; act D->B-frag via wave-private LDS roundtrip (no barriers);
// weights pre-arranged in fragment order, staged via pf-register prefetch
// (overlaps compute) + linear LDS writes.

#define N_DIMS 6
#define HID    128
#define BS     65536

typedef __attribute__((ext_vector_type(8))) short bf16x8;
typedef __attribute__((ext_vector_type(4))) float f32x4;

// d_ws byte offsets
#define SB0   0        // Win K32-pad  [Wa 8K | Wb 8K]
#define SB1   16384    // W0  fwd      [Wa 32K | Wb 32K]
#define SB2   81920    // W1  fwd
#define SB3   147456   // W2  fwd
#define SB4   212992   // W2T
#define SB5   278528   // W1T
#define SB6   344064   // W0T
#define SB7   409600   // WinT pad     [Wa 4K | Wb 4K]
#define UCOFF 417792   // u[128] f32, c at [128]

__device__ __forceinline__ float fast_tanh(float x) {
  float e = __expf(2.0f * x);
  return 1.0f - 2.0f * __builtin_amdgcn_rcpf(e + 1.0f);
}
// f32 -> packed u32 [bf16hi | bf16lo], both RNE; hi+lo ~= t to 2^-17 rel
__device__ __forceinline__ unsigned packsplit(float t) {
  unsigned u = __builtin_bit_cast(unsigned, t);
  unsigned hi = (u + 0x7fffu + ((u >> 16) & 1u)) & 0xffff0000u;
  float lo = t - __builtin_bit_cast(float, hi);
  unsigned ul = __builtin_bit_cast(unsigned, lo);
  unsigned lob = (ul + 0x7fffu + ((ul >> 16) & 1u)) >> 16;
  return hi | lob;
}

__device__ __forceinline__ void mfma3(f32x4& acc, bf16x8 wa, bf16x8 wb,
                                      bf16x8 xa, bf16x8 xb) {
  acc = __builtin_amdgcn_mfma_f32_16x16x32_bf16(wa, xa, acc, 0, 0, 0);
  acc = __builtin_amdgcn_mfma_f32_16x16x32_bf16(wa, xb, acc, 0, 0, 0);
  acc = __builtin_amdgcn_mfma_f32_16x16x32_bf16(wb, xa, acc, 0, 0, 0);
}

// ---------------- setup: fragment-per-thread weight images + u,c ----------------
__global__ __launch_bounds__(256)
void cbf_setup(const float* __restrict__ w_h, const float* __restrict__ w_in,
               const float* __restrict__ w_out, const float* __restrict__ b_h,
               const float* __restrict__ b_out, char* __restrict__ ws)
{
  const int f = blockIdx.x * 256 + threadIdx.x;
  if (f < 6144) {
    // fwd images: fragment = (r, c-octet) of layer L; idx math == R5
    const int L = f >> 11, frag = f & 2047;
    const int r = frag & 127, c0 = (frag >> 7) << 3;
    const float* src = w_h + L * 16384 + r * 128 + c0;
    bf16x8 hi, lo;
    #pragma unroll
    for (int j = 0; j < 8; ++j) {
      const unsigned pk = packsplit(src[j]);
      hi[j] = (short)(pk >> 16); lo[j] = (short)(pk & 0xffffu);
    }
    const int idx8 = ((r >> 4) * 4 + (c0 >> 5)) * 64 + ((c0 >> 3) & 3) * 16 + (r & 15);
    short* Wa = (short*)(ws + SB1 + L * 65536);
    *(bf16x8*)(Wa + idx8 * 8) = hi;
    *(bf16x8*)(Wa + 16384 + idx8 * 8) = lo;
  } else if (f < 12288) {
    // bwd (transposed) images: fragment = (c, r-octet); rows = c(k')
    const int g = f - 6144;
    const int L = g >> 11, frag = g & 2047;
    const int c = frag & 127, r0 = (frag >> 7) << 3;
    const float* src = w_h + L * 16384 + r0 * 128 + c;
    bf16x8 hi, lo;
    #pragma unroll
    for (int j = 0; j < 8; ++j) {
      const unsigned pk = packsplit(src[j * 128]);
      hi[j] = (short)(pk >> 16); lo[j] = (short)(pk & 0xffffu);
    }
    const int idx8 = ((c >> 4) * 4 + (r0 >> 5)) * 64 + ((r0 >> 3) & 3) * 16 + (c & 15);
    short* Wa = (short*)(ws + SB6 - L * 65536);   // L0->SB6, L1->SB5, L2->SB4
    *(bf16x8*)(Wa + idx8 * 8) = hi;
    *(bf16x8*)(Wa + 16384 + idx8 * 8) = lo;
  } else if (f < 12800) {
    // Win K32-pad: fragment = (r, c-octet), c<6 real
    const int frag = f - 12288;
    const int r = frag & 127, c0 = (frag >> 7) << 3;
    bf16x8 hi, lo;
    #pragma unroll
    for (int j = 0; j < 8; ++j) {
      const int c = c0 + j;
      const unsigned pk = (c < 6) ? packsplit(w_in[r * 6 + c]) : 0u;
      hi[j] = (short)(pk >> 16); lo[j] = (short)(pk & 0xffffu);
    }
    const int idx8 = (r >> 4) * 64 + ((c0 >> 3) & 3) * 16 + (r & 15);
    short* Wa = (short*)(ws + SB0);
    *(bf16x8*)(Wa + idx8 * 8) = hi;
    *(bf16x8*)(Wa + 4096 + idx8 * 8) = lo;
  } else if (f < 13056) {
    // WinT pad: fragment = (d, k-octet), d<6 real
    const int frag = f - 12800;
    const int d = frag & 15, k0 = (frag >> 4) << 3;
    bf16x8 hi, lo;
    #pragma unroll
    for (int j = 0; j < 8; ++j) {
      const unsigned pk = (d < 6) ? packsplit(w_in[(k0 + j) * 6 + d]) : 0u;
      hi[j] = (short)(pk >> 16); lo[j] = (short)(pk & 0xffffu);
    }
    const int idx8 = (k0 >> 5) * 64 + ((k0 >> 3) & 3) * 16 + d;
    short* Wa = (short*)(ws + SB7);
    *(bf16x8*)(Wa + idx8 * 8) = hi;
    *(bf16x8*)(Wa + 2048 + idx8 * 8) = lo;
  } else {
    // u = W3^T w_out, c = w_out.b3 + b_out  (block 51)
    const int t = threadIdx.x;
    float* ucp = (float*)(ws + UCOFF);
    const float* w3 = w_h + 3 * 16384;
    if (t < 128) {
      float acc = 0.f;
      #pragma unroll 4
      for (int h = 0; h < 128; ++h)
        acc = fmaf(w_out[h], w3[h * 128 + t], acc);
      ucp[t] = acc;
    } else if (t == 128) {
      float acc = b_out[0];
      for (int h = 0; h < 128; ++h)
        acc = fmaf(w_out[h], b_h[3 * HID + h], acc);
      ucp[128] = acc;
    }
  }
}

// ---------------- main kernel helpers (== R5) ----------------
template<int CNT>
__device__ __forceinline__ void pf_load(const char* ws, int sbase, int tid, float4* pf) {
  const float4* s = (const float4*)(ws + sbase);
  #pragma unroll
  for (int k = 0; k < CNT; ++k) pf[k] = s[k * 512 + tid];
}
template<int CNT>
__device__ __forceinline__ void st_write(char* Wbuf, int tid, const float4* pf) {
  #pragma unroll
  for (int k = 0; k < CNT; ++k) *(float4*)(Wbuf + (k * 512 + tid) * 16) = pf[k];
}

__device__ __forceinline__ void layer128(const char* Wbuf, int lane,
                                         const bf16x8* xa, const bf16x8* xb,
                                         f32x4* acc) {
  #pragma unroll
  for (int ht = 0; ht < 8; ++ht) {
    acc[ht] = (f32x4){0.f, 0.f, 0.f, 0.f};
    #pragma unroll
    for (int ch = 0; ch < 4; ++ch) {
      const bf16x8 wa = *(const bf16x8*)(Wbuf + (ht * 4 + ch) * 1024 + lane * 16);
      const bf16x8 wb = *(const bf16x8*)(Wbuf + 32768 + (ht * 4 + ch) * 1024 + lane * 16);
      mfma3(acc[ht], wa, wb, xa[ch], xb[ch]);
    }
  }
}

__device__ __forceinline__ void rt_read(const char* act, int l15, int lg,
                                        bf16x8* xa, bf16x8* xb) {
  const int m = (l15 << 1) & 31;
  #pragma unroll
  for (int ch = 0; ch < 4; ++ch) {
    const int g0 = (ch * 8 + lg * 2) ^ m;
    const uint4 q0 = *(const uint4*)(act + (l15 * 32 + g0) * 16);
    const uint4 q1 = *(const uint4*)(act + (l15 * 32 + (g0 | 1)) * 16);
    uint4 A, B;
    A.x = __builtin_amdgcn_perm(q0.y, q0.x, 0x07060302u);
    A.y = __builtin_amdgcn_perm(q0.w, q0.z, 0x07060302u);
    A.z = __builtin_amdgcn_perm(q1.y, q1.x, 0x07060302u);
    A.w = __builtin_amdgcn_perm(q1.w, q1.z, 0x07060302u);
    B.x = __builtin_amdgcn_perm(q0.y, q0.x, 0x05040100u);
    B.y = __builtin_amdgcn_perm(q0.w, q0.z, 0x05040100u);
    B.z = __builtin_amdgcn_perm(q1.y, q1.x, 0x05040100u);
    B.w = __builtin_amdgcn_perm(q1.w, q1.z, 0x05040100u);
    xa[ch] = __builtin_bit_cast(bf16x8, A);
    xb[ch] = __builtin_bit_cast(bf16x8, B);
  }
}

__device__ __forceinline__ void rt_write_tile(char* act, int l15, int lg, int ht,
                                              unsigned q0, unsigned q1,
                                              unsigned q2, unsigned q3) {
  const int m = (l15 << 1) & 31;
  *(uint4*)(act + (l15 * 32 + ((ht * 4 + lg) ^ m)) * 16) = (uint4){q0, q1, q2, q3};
}

// ---------------- main fused kernel (== R5 except launch bounds) ----------------
__global__ __launch_bounds__(512, 1)
void cbf_main(const float* __restrict__ x, const float* __restrict__ xc,
              const float* __restrict__ xr, const float* __restrict__ b_in,
              const float* __restrict__ b_h, const char* __restrict__ ws,
              float* __restrict__ out)
{
  extern __shared__ char lds[];               // [64K weights][8 x 8K act]
  const int tid  = threadIdx.x;
  const int lane = tid & 63;
  const int wid  = __builtin_amdgcn_readfirstlane(tid >> 6);
  const int l15  = lane & 15;
  const int lg   = lane >> 4;
  const int gsmp = blockIdx.x * 128 + wid * 16 + l15;

  char* Wbuf = lds;
  char* act  = lds + 65536 + wid * 8192;
  const float* uc = (const float*)(ws + UCOFF);
  const float cval = uc[128];

  float4 pf[8];
  pf_load<2>(ws, SB0, tid, pf);
  st_write<2>(Wbuf, tid, pf);
  __syncthreads();

  bf16x8 fa[4], fb[4];
  f32x4 acc[8];
  float D0_[32], D1_[32], D2_[32];

  // ---- phase 0: Win (K=32 padded, 1 chunk) -> A0, D0 ----
  pf_load<8>(ws, SB1, tid, pf);
  {
    float xn[6];
    #pragma unroll
    for (int d = 0; d < 6; ++d)
      xn[d] = (x[gsmp * 6 + d] - xc[d]) / xr[d];
    unsigned p[8];
    #pragma unroll
    for (int j = 0; j < 8; ++j) {
      unsigned v = (j < 6) ? packsplit(xn[j < 6 ? j : 0]) : 0u;
      p[j] = (lg == 0) ? v : 0u;
    }
    uint4 A, B;
    A.x = __builtin_amdgcn_perm(p[1], p[0], 0x07060302u);
    A.y = __builtin_amdgcn_perm(p[3], p[2], 0x07060302u);
    A.z = __builtin_amdgcn_perm(p[5], p[4], 0x07060302u);
    A.w = 0u;
    B.x = __builtin_amdgcn_perm(p[1], p[0], 0x05040100u);
    B.y = __builtin_amdgcn_perm(p[3], p[2], 0x05040100u);
    B.z = __builtin_amdgcn_perm(p[5], p[4], 0x05040100u);
    B.w = 0u;
    const bf16x8 xna = __builtin_bit_cast(bf16x8, A);
    const bf16x8 xnb = __builtin_bit_cast(bf16x8, B);
    #pragma unroll
    for (int ht = 0; ht < 8; ++ht) {
      acc[ht] = (f32x4){0.f, 0.f, 0.f, 0.f};
      const bf16x8 wa = *(const bf16x8*)(Wbuf + ht * 1024 + lane * 16);
      const bf16x8 wb = *(const bf16x8*)(Wbuf + 8192 + ht * 1024 + lane * 16);
      mfma3(acc[ht], wa, wb, xna, xnb);
    }
    #pragma unroll
    for (int ht = 0; ht < 8; ++ht) {
      const float4 b4 = *(const float4*)(b_in + ht * 16 + lg * 4);
      unsigned q[4];
      #pragma unroll
      for (int r = 0; r < 4; ++r) {
        const float t = fast_tanh(acc[ht][r] + ((const float*)&b4)[r]);
        D0_[ht * 4 + r] = fmaf(-t, t, 1.0f);
        q[r] = packsplit(t);
      }
      rt_write_tile(act, l15, lg, ht, q[0], q[1], q[2], q[3]);
    }
    rt_read(act, l15, lg, fa, fb);
  }
  __syncthreads();
  st_write<8>(Wbuf, tid, pf);
  __syncthreads();

  // ---- phases 1,2: W0 -> A1,D1 ; W1 -> A2,D2 ----
  #define FWD_PHASE(SBNEXT, BIAS, DARR)                                        \
  {                                                                            \
    pf_load<8>(ws, SBNEXT, tid, pf);                                           \
    layer128(Wbuf, lane, fa, fb, acc);                                         \
    _Pragma("unroll")                                                          \
    for (int ht = 0; ht < 8; ++ht) {                                           \
      const float4 b4 = *(const float4*)((BIAS) + ht * 16 + lg * 4);           \
      unsigned q[4];                                                           \
      _Pragma("unroll")                                                        \
      for (int r = 0; r < 4; ++r) {                                            \
        const float t = fast_tanh(acc[ht][r] + ((const float*)&b4)[r]);        \
        DARR[ht * 4 + r] = fmaf(-t, t, 1.0f);                                  \
        q[r] = packsplit(t);                                                   \
      }                                                                        \
      rt_write_tile(act, l15, lg, ht, q[0], q[1], q[2], q[3]);                 \
    }                                                                          \
    rt_read(act, l15, lg, fa, fb);                                             \
    __syncthreads();                                                           \
    st_write<8>(Wbuf, tid, pf);                                                \
    __syncthreads();                                                           \
  }
  FWD_PHASE(SB2, b_h, D1_)
  FWD_PHASE(SB3, b_h + HID, D2_)

  // ---- phase 3: W2 -> A3; V = u.A3 + c; g3 = u*(1-A3^2) ----
  {
    pf_load<8>(ws, SB4, tid, pf);
    layer128(Wbuf, lane, fa, fb, acc);
    float vp = 0.f;
    #pragma unroll
    for (int ht = 0; ht < 8; ++ht) {
      const float4 b4 = *(const float4*)(b_h + 2 * HID + ht * 16 + lg * 4);
      const float4 u4 = *(const float4*)(uc + ht * 16 + lg * 4);
      unsigned q[4];
      #pragma unroll
      for (int r = 0; r < 4; ++r) {
        const float t = fast_tanh(acc[ht][r] + ((const float*)&b4)[r]);
        const float uu = ((const float*)&u4)[r];
        vp = fmaf(uu, t, vp);
        q[r] = packsplit(uu * fmaf(-t, t, 1.0f));
      }
      rt_write_tile(act, l15, lg, ht, q[0], q[1], q[2], q[3]);
    }
    vp += __shfl_xor(vp, 16);
    vp += __shfl_xor(vp, 32);
    if (lg == 0) out[gsmp] = vp + cval;
    rt_read(act, l15, lg, fa, fb);
    __syncthreads();
    st_write<8>(Wbuf, tid, pf);
    __syncthreads();
  }

  // ---- phases 4,5,6: g2 = D2*(W2T g3); g1 = D1*(W1T g2); g0 = D0*(W0T g1) ----
  #define BWD_PHASE(SBNEXT, PFCNT, DARR)                                       \
  {                                                                            \
    pf_load<PFCNT>(ws, SBNEXT, tid, pf);                                       \
    layer128(Wbuf, lane, fa, fb, acc);                                         \
    _Pragma("unroll")                                                          \
    for (int ht = 0; ht < 8; ++ht) {                                           \
      unsigned q[4];                                                           \
      _Pragma("unroll")                                                        \
      for (int r = 0; r < 4; ++r)                                              \
        q[r] = packsplit(acc[ht][r] * DARR[ht * 4 + r]);                       \
      rt_write_tile(act, l15, lg, ht, q[0], q[1], q[2], q[3]);                 \
    }                                                                          \
    rt_read(act, l15, lg, fa, fb);                                             \
    __syncthreads();                                                           \
    st_write<PFCNT>(Wbuf, tid, pf);                                            \
    __syncthreads();                                                           \
  }
  BWD_PHASE(SB5, 8, D2_)
  BWD_PHASE(SB6, 8, D1_)
  BWD_PHASE(SB7, 1, D0_)

  // ---- phase 7: WinT -> J rows = dim (0..5 valid) ----
  {
    f32x4 aj = (f32x4){0.f, 0.f, 0.f, 0.f};
    #pragma unroll
    for (int ch = 0; ch < 4; ++ch) {
      const bf16x8 wa = *(const bf16x8*)(Wbuf + ch * 1024 + lane * 16);
      const bf16x8 wb = *(const bf16x8*)(Wbuf + 4096 + ch * 1024 + lane * 16);
      mfma3(aj, wa, wb, fa[ch], fb[ch]);
    }
    #pragma unroll
    for (int r = 0; r < 4; ++r) {
      const int d = lg * 4 + r;
      if (d < 6) out[BS + gsmp * 6 + d] = aj[r] / xr[d];
    }
  }
}

extern "C" void kernel_launch(void* const* d_in, const int* in_sizes, int n_in,
                              void* d_out, int out_size, void* d_ws, size_t ws_size,
                              hipStream_t stream) {
  const float* x     = (const float*)d_in[0];
  const float* xc    = (const float*)d_in[1];
  const float* xr    = (const float*)d_in[2];
  const float* w_in  = (const float*)d_in[3];
  const float* b_in  = (const float*)d_in[4];
  const float* w_h   = (const float*)d_in[5];
  const float* b_h   = (const float*)d_in[6];
  const float* w_out = (const float*)d_in[7];
  const float* b_out = (const float*)d_in[8];
  float* out = (float*)d_out;
  char* ws   = (char*)d_ws;

  cbf_setup<<<dim3(52), dim3(256), 0, stream>>>(w_h, w_in, w_out, b_h, b_out, ws);

  const size_t shmem = 65536 + 8 * 8192;      // 131072 B
  (void)hipFuncSetAttribute((const void*)cbf_main,
                            hipFuncAttributeMaxDynamicSharedMemorySize,
                            (int)shmem);
  cbf_main<<<dim3(BS / 128), dim3(512), shmem, stream>>>(
      x, xc, xr, b_in, b_h, ws, out);
}